// Round 7
// baseline (154.403 us; speedup 1.0000x reference)
//
#include <hip/hip_runtime.h>
#include <cstdint>

#define B_SZ   4
#define E_DIM  16
#define C_INST 24
#define HW_N   262144          // 512*512
#define NG     (HW_N / 4)      // 65536 float4 pixel-groups per (b, e)

#define DELTA_VAR  0.75f
#define DELTA_DIST 2.0f
#define ALPHA_W 1.0f
#define BETA_W  1.0f
#define GAMMA_W 0.001f

#define P1_NB   16                       // chunks per (dim-plane, b)
#define P1_ITER (NG / (P1_NB * 256))     // 16 == E_DIM (count-fold trick)
#define P2_TOTAL_BLOCKS (256 * B_SZ)     // 1024

// ---------------------------------------------------------------------------
// Pass 1: lane-private LDS bucket segment-sums, ONE dim per plane
// (25.6 KB -> 6 blocks/CU; R6's 2-dim variant halved occupancy for no gain).
// Counts folded via __ballot/popc on iteration it==eg: each (b,chunk,iter)
// slice is counted by exactly one of the 16 planes -> no dedicated count
// plane, labels swept 16x not 17x.
// ---------------------------------------------------------------------------
__global__ __launch_bounds__(256) void pass1_kernel(
    const float* __restrict__ input, const int* __restrict__ target,
    float* __restrict__ sums, float* __restrict__ counts)
{
    __shared__ float buk[256][25];       // 24 + 1 pad; odd stride spreads banks
    __shared__ float crow[4][C_INST];
    const int tid  = threadIdx.x;
    const int lane = tid & 63;
    const int wv   = tid >> 6;
    const int chunk = blockIdx.x;
    const int eg    = blockIdx.y;        // 0..15 = embedding dim
    const int b     = blockIdx.z;

    float* __restrict__ myrow = &buk[tid][0];
    #pragma unroll
    for (int j = 0; j < C_INST; ++j) myrow[j] = 0.f;   // own row: no sync

    const int4* __restrict__ tgt4 = (const int4*)(target + (size_t)b * HW_N);
    const float4* __restrict__ src4 =
        (const float4*)(input + ((size_t)b * E_DIM + eg) * HW_N);
    const int gbase = chunk * 256 * P1_ITER + tid;

    int scnt[C_INST];
    #pragma unroll
    for (int c = 0; c < C_INST; ++c) scnt[c] = 0;

    int4   lab = tgt4[gbase];
    float4 x   = src4[gbase];
    #pragma unroll
    for (int it = 0; it < P1_ITER; ++it) {
        const int4   lc = lab;
        const float4 xc = x;
        if (it + 1 < P1_ITER) {          // register prefetch
            lab = tgt4[gbase + (it + 1) * 256];
            x   = src4[gbase + (it + 1) * 256];
        }
        myrow[lc.x] += xc.x;
        myrow[lc.y] += xc.y;
        myrow[lc.z] += xc.z;
        myrow[lc.w] += xc.w;
        if (it == eg) {                  // uniform branch: count this slice
            #pragma unroll
            for (int c = 0; c < C_INST; ++c) {
                scnt[c] += (int)__popcll(__ballot(lc.x == c))
                         + (int)__popcll(__ballot(lc.y == c))
                         + (int)__popcll(__ballot(lc.z == c))
                         + (int)__popcll(__ballot(lc.w == c));
            }
        }
    }
    if (lane == 0) {
        #pragma unroll
        for (int c = 0; c < C_INST; ++c) crow[wv][c] = (float)scnt[c];
    }
    __syncthreads();

    // reduce 256 bucket rows -> 24 class sums; 8 threads per class
    if (tid < 8 * C_INST) {
        const int c  = tid >> 3;
        const int r0 = tid & 7;
        float s = 0.f;
        #pragma unroll
        for (int i = 0; i < 32; ++i) s += buk[8 * i + r0][c];
        s += __shfl_xor(s, 1, 64);
        s += __shfl_xor(s, 2, 64);
        s += __shfl_xor(s, 4, 64);
        if (r0 == 0)
            unsafeAtomicAdd(&sums[((size_t)b * E_DIM + eg) * C_INST + c], s);
    }
    if (tid < C_INST) {
        const float s = crow[0][tid] + crow[1][tid] + crow[2][tid] + crow[3][tid];
        unsafeAtomicAdd(&counts[b * C_INST + tid], s);
    }
}

// ---------------------------------------------------------------------------
// Pass 2 + fused final. Variance term as one scalar (h^2/cnt[lab]).
// mu stride 17 floats: bank=(17c+e)%32, 17 coprime 32 -> conflict-free
// gathers (was stride 20: 8 bank-groups, ~3-way). e-loop chunked (8 float4s
// live -> ~60 VGPR, 8 waves/SIMD). Last block (fenced ticket) computes the
// pairwise + regularizer terms and writes the loss — no 3rd kernel.
// ---------------------------------------------------------------------------
__global__ __launch_bounds__(256) void pass2_kernel(
    const float* __restrict__ input, const int* __restrict__ target,
    const float* __restrict__ sums, const float* __restrict__ counts,
    float* __restrict__ loss_acc, unsigned int* __restrict__ done,
    float* __restrict__ out)
{
    __shared__ float mu_l[C_INST][17];
    __shared__ float w_l[C_INST];
    __shared__ float redw[4];
    __shared__ int lastf;
    const int tid  = threadIdx.x;
    const int lane = tid & 63;
    const int wv   = tid >> 6;
    const int b    = blockIdx.y;

    if (tid < C_INST) {
        const float cv = counts[b * C_INST + tid];
        w_l[tid] = (cv > 0.f) ? 1.f / cv : 0.f;
    }
    __syncthreads();
    for (int i = tid; i < E_DIM * C_INST; i += 256) {
        const int e = i / C_INST, c = i % C_INST;
        mu_l[c][e] = sums[((size_t)b * E_DIM + e) * C_INST + c] * w_l[c];
    }
    __syncthreads();

    const int g = blockIdx.x * 256 + tid;    // 256 blocks/batch
    const int4 lab4 = ((const int4*)(target + (size_t)b * HW_N))[g];
    const float4* __restrict__ src4 =
        (const float4*)(input + (size_t)b * E_DIM * HW_N);

    float d2[4] = {0.f, 0.f, 0.f, 0.f};
    #pragma unroll
    for (int e8 = 0; e8 < 2; ++e8) {
        float4 xv[8];
        #pragma unroll
        for (int e = 0; e < 8; ++e)
            xv[e] = src4[(size_t)(e8 * 8 + e) * NG + g];
        #pragma unroll
        for (int e = 0; e < 8; ++e) {
            const int ee = e8 * 8 + e;
            float df;
            df = xv[e].x - mu_l[lab4.x][ee]; d2[0] = fmaf(df, df, d2[0]);
            df = xv[e].y - mu_l[lab4.y][ee]; d2[1] = fmaf(df, df, d2[1]);
            df = xv[e].z - mu_l[lab4.z][ee]; d2[2] = fmaf(df, df, d2[2]);
            df = xv[e].w - mu_l[lab4.w][ee]; d2[3] = fmaf(df, df, d2[3]);
        }
    }

    float vloc = 0.f;
    {
        const int lp[4] = {lab4.x, lab4.y, lab4.z, lab4.w};
        #pragma unroll
        for (int p = 0; p < 4; ++p) {
            const float h = fmaxf(sqrtf(d2[p]) - DELTA_VAR, 0.f);
            vloc = fmaf(h * h, w_l[lp[p]], vloc);
        }
    }
    #pragma unroll
    for (int m = 1; m < 64; m <<= 1) vloc += __shfl_xor(vloc, m, 64);
    if (lane == 0) redw[wv] = vloc;
    __syncthreads();

    if (tid == 0) {
        unsafeAtomicAdd(loss_acc, redw[0] + redw[1] + redw[2] + redw[3]);
        __threadfence();
        const unsigned int t = atomicAdd(done, 1u);
        lastf = (t == P2_TOTAL_BLOCKS - 1) ? 1 : 0;
    }
    __syncthreads();

    // ---- fused final phase: only the last-finishing block ----
    if (lastf) {
        __shared__ float mu3[B_SZ][C_INST][E_DIM];
        __shared__ float red[256];
        for (int i = tid; i < B_SZ * C_INST * E_DIM; i += 256) {
            const int bb = i / (C_INST * E_DIM);
            const int r  = i % (C_INST * E_DIM);
            const int e  = r / C_INST, c = r % C_INST;
            const float cv = counts[bb * C_INST + c];
            mu3[bb][c][e] = (cv > 0.f)
                ? sums[((size_t)bb * E_DIM + e) * C_INST + c] / cv : 0.f;
        }
        __syncthreads();

        float acc = 0.f;
        for (int i = tid; i < B_SZ * C_INST; i += 256) {
            const int bb = i / C_INST, c = i % C_INST;
            float n2 = 0.f;
            #pragma unroll
            for (int e = 0; e < E_DIM; ++e) n2 += mu3[bb][c][e] * mu3[bb][c][e];
            acc += GAMMA_W * sqrtf(n2) * (1.0f / (B_SZ * C_INST));
        }
        for (int i = tid; i < B_SZ * C_INST * C_INST; i += 256) {
            const int bb = i / (C_INST * C_INST);
            const int r  = i % (C_INST * C_INST);
            const int c1 = r / C_INST, c2 = r % C_INST;
            if (c1 != c2) {
                float dd2 = 0.f;
                #pragma unroll
                for (int e = 0; e < E_DIM; ++e) {
                    const float d = mu3[bb][c1][e] - mu3[bb][c2][e];
                    dd2 += d * d;
                }
                const float h = fmaxf(2.0f * DELTA_DIST - sqrtf(dd2), 0.f);
                acc += BETA_W * h * h * (1.0f / (B_SZ * C_INST * (C_INST - 1)));
            }
        }

        red[tid] = acc;
        __syncthreads();
        for (int s = 128; s > 0; s >>= 1) {
            if (tid < s) red[tid] += red[tid + s];
            __syncthreads();
        }
        if (tid == 0) {
            const float vsum = atomicAdd(loss_acc, 0.0f);  // coherent read
            out[0] = red[0] + ALPHA_W * vsum * (1.0f / (B_SZ * C_INST));
        }
    }
}

extern "C" void kernel_launch(void* const* d_in, const int* in_sizes, int n_in,
                              void* d_out, int out_size, void* d_ws, size_t ws_size,
                              hipStream_t stream)
{
    const float* input  = (const float*)d_in[0];
    const int*   target = (const int*)d_in[1];

    float* sums     = (float*)d_ws;                         // B*E*C ([b][e][c])
    float* counts   = sums + B_SZ * E_DIM * C_INST;         // B*C
    float* loss_acc = counts + B_SZ * C_INST;               // 1
    unsigned int* done = (unsigned int*)(loss_acc + 1);     // 1
    const size_t ws_bytes =
        (size_t)(B_SZ * E_DIM * C_INST + B_SZ * C_INST + 2) * sizeof(float);
    hipMemsetAsync(d_ws, 0, ws_bytes, stream);

    pass1_kernel<<<dim3(P1_NB, E_DIM, B_SZ), 256, 0, stream>>>(input, target, sums, counts);
    pass2_kernel<<<dim3(256, B_SZ), 256, 0, stream>>>(input, target, sums, counts,
                                                      loss_acc, done, (float*)d_out);
}

// Round 8
// 152.653 us; speedup vs baseline: 1.0115x; 1.0115x over previous
//
#include <hip/hip_runtime.h>
#include <cstdint>

#define B_SZ   4
#define E_DIM  16
#define C_INST 24
#define HW_N   262144          // 512*512
#define NG     (HW_N / 4)      // 65536 float4 pixel-groups per (b, e)

#define DELTA_VAR  0.75f
#define DELTA_DIST 2.0f
#define ALPHA_W 1.0f
#define BETA_W  1.0f
#define GAMMA_W 0.001f

#define P1_NB   16                       // chunks per (dim-plane, b)
#define P1_ITER (NG / (P1_NB * 256))     // 16 == E_DIM (count-fold trick)
#define P2_TOTAL_BLOCKS (256 * B_SZ)     // 1024

// ---------------------------------------------------------------------------
// Pass 1 (UNCHANGED from R7 — measured ~18 us, near its ~14 us floor):
// lane-private LDS bucket segment-sums, one dim per plane, counts folded
// via __ballot/popc on iteration it==eg.
// ---------------------------------------------------------------------------
__global__ __launch_bounds__(256) void pass1_kernel(
    const float* __restrict__ input, const int* __restrict__ target,
    float* __restrict__ sums, float* __restrict__ counts)
{
    __shared__ float buk[256][25];       // 24 + 1 pad; odd stride spreads banks
    __shared__ float crow[4][C_INST];
    const int tid  = threadIdx.x;
    const int lane = tid & 63;
    const int wv   = tid >> 6;
    const int chunk = blockIdx.x;
    const int eg    = blockIdx.y;        // 0..15 = embedding dim
    const int b     = blockIdx.z;

    float* __restrict__ myrow = &buk[tid][0];
    #pragma unroll
    for (int j = 0; j < C_INST; ++j) myrow[j] = 0.f;   // own row: no sync

    const int4* __restrict__ tgt4 = (const int4*)(target + (size_t)b * HW_N);
    const float4* __restrict__ src4 =
        (const float4*)(input + ((size_t)b * E_DIM + eg) * HW_N);
    const int gbase = chunk * 256 * P1_ITER + tid;

    int scnt[C_INST];
    #pragma unroll
    for (int c = 0; c < C_INST; ++c) scnt[c] = 0;

    int4   lab = tgt4[gbase];
    float4 x   = src4[gbase];
    #pragma unroll
    for (int it = 0; it < P1_ITER; ++it) {
        const int4   lc = lab;
        const float4 xc = x;
        if (it + 1 < P1_ITER) {          // register prefetch
            lab = tgt4[gbase + (it + 1) * 256];
            x   = src4[gbase + (it + 1) * 256];
        }
        myrow[lc.x] += xc.x;
        myrow[lc.y] += xc.y;
        myrow[lc.z] += xc.z;
        myrow[lc.w] += xc.w;
        if (it == eg) {                  // uniform branch: count this slice
            #pragma unroll
            for (int c = 0; c < C_INST; ++c) {
                scnt[c] += (int)__popcll(__ballot(lc.x == c))
                         + (int)__popcll(__ballot(lc.y == c))
                         + (int)__popcll(__ballot(lc.z == c))
                         + (int)__popcll(__ballot(lc.w == c));
            }
        }
    }
    if (lane == 0) {
        #pragma unroll
        for (int c = 0; c < C_INST; ++c) crow[wv][c] = (float)scnt[c];
    }
    __syncthreads();

    // reduce 256 bucket rows -> 24 class sums; 8 threads per class
    if (tid < 8 * C_INST) {
        const int c  = tid >> 3;
        const int r0 = tid & 7;
        float s = 0.f;
        #pragma unroll
        for (int i = 0; i < 32; ++i) s += buk[8 * i + r0][c];
        s += __shfl_xor(s, 1, 64);
        s += __shfl_xor(s, 2, 64);
        s += __shfl_xor(s, 4, 64);
        if (r0 == 0)
            unsafeAtomicAdd(&sums[((size_t)b * E_DIM + eg) * C_INST + c], s);
    }
    if (tid < C_INST) {
        const float s = crow[0][tid] + crow[1][tid] + crow[2][tid] + crow[3][tid];
        unsafeAtomicAdd(&counts[b * C_INST + tid], s);
    }
}

// ---------------------------------------------------------------------------
// Pass 2 + fused final. R8: ALL 16 float4 loads issued up-front into a
// register array (live set ~90 VGPR -> 16 loads in flight; R7's 2x8
// chunking let the compiler serialize to ~2 in flight, VGPR=32, +27 us).
// mu stride 17 (conflict-free gathers). Last block (fenced ticket) computes
// pairwise + regularizer and writes the loss.
// ---------------------------------------------------------------------------
__global__ __launch_bounds__(256) void pass2_kernel(
    const float* __restrict__ input, const int* __restrict__ target,
    const float* __restrict__ sums, const float* __restrict__ counts,
    float* __restrict__ loss_acc, unsigned int* __restrict__ done,
    float* __restrict__ out)
{
    __shared__ float mu_l[C_INST][17];
    __shared__ float w_l[C_INST];
    __shared__ float redw[4];
    __shared__ int lastf;
    const int tid  = threadIdx.x;
    const int lane = tid & 63;
    const int wv   = tid >> 6;
    const int b    = blockIdx.y;

    if (tid < C_INST) {
        const float cv = counts[b * C_INST + tid];
        w_l[tid] = (cv > 0.f) ? 1.f / cv : 0.f;
    }
    __syncthreads();
    for (int i = tid; i < E_DIM * C_INST; i += 256) {
        const int e = i / C_INST, c = i % C_INST;
        mu_l[c][e] = sums[((size_t)b * E_DIM + e) * C_INST + c] * w_l[c];
    }
    __syncthreads();

    const int g = blockIdx.x * 256 + tid;    // 256 blocks/batch
    const int4 lab4 = ((const int4*)(target + (size_t)b * HW_N))[g];
    const float4* __restrict__ src4 =
        (const float4*)(input + (size_t)b * E_DIM * HW_N);

    // ALL loads first — keep 16 independent float4 loads in flight
    float4 xv[E_DIM];
    #pragma unroll
    for (int e = 0; e < E_DIM; ++e)
        xv[e] = src4[(size_t)e * NG + g];

    float d2[4] = {0.f, 0.f, 0.f, 0.f};
    #pragma unroll
    for (int e = 0; e < E_DIM; ++e) {
        float df;
        df = xv[e].x - mu_l[lab4.x][e]; d2[0] = fmaf(df, df, d2[0]);
        df = xv[e].y - mu_l[lab4.y][e]; d2[1] = fmaf(df, df, d2[1]);
        df = xv[e].z - mu_l[lab4.z][e]; d2[2] = fmaf(df, df, d2[2]);
        df = xv[e].w - mu_l[lab4.w][e]; d2[3] = fmaf(df, df, d2[3]);
    }

    float vloc = 0.f;
    {
        const int lp[4] = {lab4.x, lab4.y, lab4.z, lab4.w};
        #pragma unroll
        for (int p = 0; p < 4; ++p) {
            const float h = fmaxf(sqrtf(d2[p]) - DELTA_VAR, 0.f);
            vloc = fmaf(h * h, w_l[lp[p]], vloc);
        }
    }
    #pragma unroll
    for (int m = 1; m < 64; m <<= 1) vloc += __shfl_xor(vloc, m, 64);
    if (lane == 0) redw[wv] = vloc;
    __syncthreads();

    if (tid == 0) {
        unsafeAtomicAdd(loss_acc, redw[0] + redw[1] + redw[2] + redw[3]);
        __threadfence();
        const unsigned int t = atomicAdd(done, 1u);
        lastf = (t == P2_TOTAL_BLOCKS - 1) ? 1 : 0;
    }
    __syncthreads();

    // ---- fused final phase: only the last-finishing block ----
    if (lastf) {
        __shared__ float mu3[B_SZ][C_INST][E_DIM];
        __shared__ float red[256];
        for (int i = tid; i < B_SZ * C_INST * E_DIM; i += 256) {
            const int bb = i / (C_INST * E_DIM);
            const int r  = i % (C_INST * E_DIM);
            const int e  = r / C_INST, c = r % C_INST;
            const float cv = counts[bb * C_INST + c];
            mu3[bb][c][e] = (cv > 0.f)
                ? sums[((size_t)bb * E_DIM + e) * C_INST + c] / cv : 0.f;
        }
        __syncthreads();

        float acc = 0.f;
        for (int i = tid; i < B_SZ * C_INST; i += 256) {
            const int bb = i / C_INST, c = i % C_INST;
            float n2 = 0.f;
            #pragma unroll
            for (int e = 0; e < E_DIM; ++e) n2 += mu3[bb][c][e] * mu3[bb][c][e];
            acc += GAMMA_W * sqrtf(n2) * (1.0f / (B_SZ * C_INST));
        }
        for (int i = tid; i < B_SZ * C_INST * C_INST; i += 256) {
            const int bb = i / (C_INST * C_INST);
            const int r  = i % (C_INST * C_INST);
            const int c1 = r / C_INST, c2 = r % C_INST;
            if (c1 != c2) {
                float dd2 = 0.f;
                #pragma unroll
                for (int e = 0; e < E_DIM; ++e) {
                    const float d = mu3[bb][c1][e] - mu3[bb][c2][e];
                    dd2 += d * d;
                }
                const float h = fmaxf(2.0f * DELTA_DIST - sqrtf(dd2), 0.f);
                acc += BETA_W * h * h * (1.0f / (B_SZ * C_INST * (C_INST - 1)));
            }
        }

        red[tid] = acc;
        __syncthreads();
        for (int s = 128; s > 0; s >>= 1) {
            if (tid < s) red[tid] += red[tid + s];
            __syncthreads();
        }
        if (tid == 0) {
            const float vsum = atomicAdd(loss_acc, 0.0f);  // coherent read
            out[0] = red[0] + ALPHA_W * vsum * (1.0f / (B_SZ * C_INST));
        }
    }
}

extern "C" void kernel_launch(void* const* d_in, const int* in_sizes, int n_in,
                              void* d_out, int out_size, void* d_ws, size_t ws_size,
                              hipStream_t stream)
{
    const float* input  = (const float*)d_in[0];
    const int*   target = (const int*)d_in[1];

    float* sums     = (float*)d_ws;                         // B*E*C ([b][e][c])
    float* counts   = sums + B_SZ * E_DIM * C_INST;         // B*C
    float* loss_acc = counts + B_SZ * C_INST;               // 1
    unsigned int* done = (unsigned int*)(loss_acc + 1);     // 1
    const size_t ws_bytes =
        (size_t)(B_SZ * E_DIM * C_INST + B_SZ * C_INST + 2) * sizeof(float);
    hipMemsetAsync(d_ws, 0, ws_bytes, stream);

    pass1_kernel<<<dim3(P1_NB, E_DIM, B_SZ), 256, 0, stream>>>(input, target, sums, counts);
    pass2_kernel<<<dim3(256, B_SZ), 256, 0, stream>>>(input, target, sums, counts,
                                                      loss_acc, done, (float*)d_out);
}

// Round 9
// 122.221 us; speedup vs baseline: 1.2633x; 1.2490x over previous
//
#include <hip/hip_runtime.h>
#include <cstdint>

#define B_SZ   4
#define E_DIM  16
#define C_INST 24
#define HW_N   262144          // 512*512
#define NG     (HW_N / 4)      // 65536 float4 pixel-groups per (b, e)

#define DELTA_VAR  0.75f
#define DELTA_DIST 2.0f
#define ALPHA_W 1.0f
#define BETA_W  1.0f
#define GAMMA_W 0.001f

#define P1_NB   16                       // chunks per (dim-plane, b)
#define P1_ITER (NG / (P1_NB * 256))     // 16 == E_DIM (count-fold trick)
#define P2_TOTAL_BLOCKS (256 * B_SZ)     // 1024

// ---------------------------------------------------------------------------
// Pass 1 (UNCHANGED — ~18 us, near floor): lane-private LDS bucket
// segment-sums, one dim per plane, counts folded via ballot at it==eg.
// Its global atomics are spread over 1632 addresses (<=16-deep chains) —
// unlike pass2's old same-address chain (R8 lesson).
// ---------------------------------------------------------------------------
__global__ __launch_bounds__(256) void pass1_kernel(
    const float* __restrict__ input, const int* __restrict__ target,
    float* __restrict__ sums, float* __restrict__ counts)
{
    __shared__ float buk[256][25];       // 24 + 1 pad; odd stride spreads banks
    __shared__ float crow[4][C_INST];
    const int tid  = threadIdx.x;
    const int lane = tid & 63;
    const int wv   = tid >> 6;
    const int chunk = blockIdx.x;
    const int eg    = blockIdx.y;        // 0..15 = embedding dim
    const int b     = blockIdx.z;

    float* __restrict__ myrow = &buk[tid][0];
    #pragma unroll
    for (int j = 0; j < C_INST; ++j) myrow[j] = 0.f;   // own row: no sync

    const int4* __restrict__ tgt4 = (const int4*)(target + (size_t)b * HW_N);
    const float4* __restrict__ src4 =
        (const float4*)(input + ((size_t)b * E_DIM + eg) * HW_N);
    const int gbase = chunk * 256 * P1_ITER + tid;

    int scnt[C_INST];
    #pragma unroll
    for (int c = 0; c < C_INST; ++c) scnt[c] = 0;

    int4   lab = tgt4[gbase];
    float4 x   = src4[gbase];
    #pragma unroll
    for (int it = 0; it < P1_ITER; ++it) {
        const int4   lc = lab;
        const float4 xc = x;
        if (it + 1 < P1_ITER) {          // register prefetch
            lab = tgt4[gbase + (it + 1) * 256];
            x   = src4[gbase + (it + 1) * 256];
        }
        myrow[lc.x] += xc.x;
        myrow[lc.y] += xc.y;
        myrow[lc.z] += xc.z;
        myrow[lc.w] += xc.w;
        if (it == eg) {                  // uniform branch: count this slice
            #pragma unroll
            for (int c = 0; c < C_INST; ++c) {
                scnt[c] += (int)__popcll(__ballot(lc.x == c))
                         + (int)__popcll(__ballot(lc.y == c))
                         + (int)__popcll(__ballot(lc.z == c))
                         + (int)__popcll(__ballot(lc.w == c));
            }
        }
    }
    if (lane == 0) {
        #pragma unroll
        for (int c = 0; c < C_INST; ++c) crow[wv][c] = (float)scnt[c];
    }
    __syncthreads();

    // reduce 256 bucket rows -> 24 class sums; 8 threads per class
    if (tid < 8 * C_INST) {
        const int c  = tid >> 3;
        const int r0 = tid & 7;
        float s = 0.f;
        #pragma unroll
        for (int i = 0; i < 32; ++i) s += buk[8 * i + r0][c];
        s += __shfl_xor(s, 1, 64);
        s += __shfl_xor(s, 2, 64);
        s += __shfl_xor(s, 4, 64);
        if (r0 == 0)
            unsafeAtomicAdd(&sums[((size_t)b * E_DIM + eg) * C_INST + c], s);
    }
    if (tid < C_INST) {
        const float s = crow[0][tid] + crow[1][tid] + crow[2][tid] + crow[3][tid];
        unsafeAtomicAdd(&counts[b * C_INST + tid], s);
    }
}

// ---------------------------------------------------------------------------
// Pass 2: variance term, per-block partial written to a DISTINCT slot
// (plain store — no same-address atomic chain; R8's 51.7us was 2048
// serialized atomics to 2 addresses, ~60cyc each = ~124K cycles).
// mu stride 17 (conflict-free gathers).
// ---------------------------------------------------------------------------
__global__ __launch_bounds__(256) void pass2_kernel(
    const float* __restrict__ input, const int* __restrict__ target,
    const float* __restrict__ sums, const float* __restrict__ counts,
    float* __restrict__ partials)
{
    __shared__ float mu_l[C_INST][17];
    __shared__ float w_l[C_INST];
    __shared__ float redw[4];
    const int tid  = threadIdx.x;
    const int lane = tid & 63;
    const int wv   = tid >> 6;
    const int b    = blockIdx.y;

    if (tid < C_INST) {
        const float cv = counts[b * C_INST + tid];
        w_l[tid] = (cv > 0.f) ? 1.f / cv : 0.f;
    }
    __syncthreads();
    for (int i = tid; i < E_DIM * C_INST; i += 256) {
        const int e = i / C_INST, c = i % C_INST;
        mu_l[c][e] = sums[((size_t)b * E_DIM + e) * C_INST + c] * w_l[c];
    }
    __syncthreads();

    const int g = blockIdx.x * 256 + tid;    // 256 blocks/batch
    const int4 lab4 = ((const int4*)(target + (size_t)b * HW_N))[g];
    const float4* __restrict__ src4 =
        (const float4*)(input + (size_t)b * E_DIM * HW_N);

    float4 xv[E_DIM];
    #pragma unroll
    for (int e = 0; e < E_DIM; ++e)
        xv[e] = src4[(size_t)e * NG + g];

    float d2[4] = {0.f, 0.f, 0.f, 0.f};
    #pragma unroll
    for (int e = 0; e < E_DIM; ++e) {
        float df;
        df = xv[e].x - mu_l[lab4.x][e]; d2[0] = fmaf(df, df, d2[0]);
        df = xv[e].y - mu_l[lab4.y][e]; d2[1] = fmaf(df, df, d2[1]);
        df = xv[e].z - mu_l[lab4.z][e]; d2[2] = fmaf(df, df, d2[2]);
        df = xv[e].w - mu_l[lab4.w][e]; d2[3] = fmaf(df, df, d2[3]);
    }

    float vloc = 0.f;
    {
        const int lp[4] = {lab4.x, lab4.y, lab4.z, lab4.w};
        #pragma unroll
        for (int p = 0; p < 4; ++p) {
            const float h = fmaxf(sqrtf(d2[p]) - DELTA_VAR, 0.f);
            vloc = fmaf(h * h, w_l[lp[p]], vloc);
        }
    }
    #pragma unroll
    for (int m = 1; m < 64; m <<= 1) vloc += __shfl_xor(vloc, m, 64);
    if (lane == 0) redw[wv] = vloc;
    __syncthreads();
    if (tid == 0)
        partials[b * 256 + blockIdx.x] = redw[0] + redw[1] + redw[2] + redw[3];
}

// ---------------------------------------------------------------------------
// Final: sum 1024 partials + pairwise distance + regularizer -> loss.
// ---------------------------------------------------------------------------
__global__ __launch_bounds__(256) void final_kernel(
    const float* __restrict__ sums, const float* __restrict__ counts,
    const float* __restrict__ partials, float* __restrict__ out)
{
    __shared__ float mu[B_SZ][C_INST][E_DIM];
    __shared__ float red[256];
    const int tid = threadIdx.x;

    for (int i = tid; i < B_SZ * C_INST * E_DIM; i += 256) {
        const int b = i / (C_INST * E_DIM);
        const int r = i % (C_INST * E_DIM);
        const int e = r / C_INST, c = r % C_INST;
        const float cv = counts[b * C_INST + c];
        mu[b][c][e] = (cv > 0.f)
            ? sums[((size_t)b * E_DIM + e) * C_INST + c] / cv : 0.f;
    }
    __syncthreads();

    float acc = 0.f;
    // variance partials (1024 slots, 4 per thread)
    #pragma unroll
    for (int i = 0; i < P2_TOTAL_BLOCKS / 256; ++i)
        acc += partials[i * 256 + tid] * (ALPHA_W / (B_SZ * C_INST));
    // regularizer
    for (int i = tid; i < B_SZ * C_INST; i += 256) {
        const int b = i / C_INST, c = i % C_INST;
        float n2 = 0.f;
        #pragma unroll
        for (int e = 0; e < E_DIM; ++e) n2 += mu[b][c][e] * mu[b][c][e];
        acc += GAMMA_W * sqrtf(n2) * (1.0f / (B_SZ * C_INST));
    }
    // pairwise repulsion
    for (int i = tid; i < B_SZ * C_INST * C_INST; i += 256) {
        const int b  = i / (C_INST * C_INST);
        const int r  = i % (C_INST * C_INST);
        const int c1 = r / C_INST, c2 = r % C_INST;
        if (c1 != c2) {
            float d2 = 0.f;
            #pragma unroll
            for (int e = 0; e < E_DIM; ++e) {
                const float d = mu[b][c1][e] - mu[b][c2][e];
                d2 += d * d;
            }
            const float h = fmaxf(2.0f * DELTA_DIST - sqrtf(d2), 0.f);
            acc += BETA_W * h * h * (1.0f / (B_SZ * C_INST * (C_INST - 1)));
        }
    }

    red[tid] = acc;
    __syncthreads();
    for (int s = 128; s > 0; s >>= 1) {
        if (tid < s) red[tid] += red[tid + s];
        __syncthreads();
    }
    if (tid == 0) out[0] = red[0];
}

extern "C" void kernel_launch(void* const* d_in, const int* in_sizes, int n_in,
                              void* d_out, int out_size, void* d_ws, size_t ws_size,
                              hipStream_t stream)
{
    const float* input  = (const float*)d_in[0];
    const int*   target = (const int*)d_in[1];

    float* sums     = (float*)d_ws;                         // B*E*C ([b][e][c])
    float* counts   = sums + B_SZ * E_DIM * C_INST;         // B*C
    float* partials = counts + B_SZ * C_INST;               // 1024 (no zeroing needed)
    const size_t ws_zero_bytes =
        (size_t)(B_SZ * E_DIM * C_INST + B_SZ * C_INST) * sizeof(float);
    hipMemsetAsync(d_ws, 0, ws_zero_bytes, stream);

    pass1_kernel<<<dim3(P1_NB, E_DIM, B_SZ), 256, 0, stream>>>(input, target, sums, counts);
    pass2_kernel<<<dim3(256, B_SZ), 256, 0, stream>>>(input, target, sums, counts, partials);
    final_kernel<<<1, 256, 0, stream>>>(sums, counts, partials, (float*)d_out);
}

// Round 10
// 121.492 us; speedup vs baseline: 1.2709x; 1.0060x over previous
//
#include <hip/hip_runtime.h>
#include <cstdint>

#define B_SZ   4
#define E_DIM  16
#define C_INST 24
#define HW_N   262144          // 512*512
#define NG     (HW_N / 4)      // 65536 float4 pixel-groups per (b, e)

#define DELTA_VAR  0.75f
#define DELTA_DIST 2.0f
#define ALPHA_W 1.0f
#define BETA_W  1.0f
#define GAMMA_W 0.001f

#define P1_NB   32                       // chunks per (dim-plane, b) — R10: 16->32
#define P1_ITER (NG / (P1_NB * 256))     // 8
#define P2_TOTAL_BLOCKS (256 * B_SZ)     // 1024

// ---------------------------------------------------------------------------
// Pass 1: lane-private LDS bucket segment-sums, one dim per plane.
// R10: grid 2048 (was 1024) — old grid gave 4 blocks/CU while 25.6 KB LDS
// allows 6; kernel is RMW-latency-bound so resident waves are the cover.
// Counts folded via ballot: plane eg<8 counts iteration it==eg (iters 0..7
// <-> planes 0..7, each (b,chunk,it) slice counted exactly once).
// ---------------------------------------------------------------------------
__global__ __launch_bounds__(256) void pass1_kernel(
    const float* __restrict__ input, const int* __restrict__ target,
    float* __restrict__ sums, float* __restrict__ counts)
{
    __shared__ float buk[256][25];       // 24 + 1 pad; odd stride spreads banks
    __shared__ float crow[4][C_INST];
    const int tid  = threadIdx.x;
    const int lane = tid & 63;
    const int wv   = tid >> 6;
    const int chunk = blockIdx.x;
    const int eg    = blockIdx.y;        // 0..15 = embedding dim
    const int b     = blockIdx.z;

    float* __restrict__ myrow = &buk[tid][0];
    #pragma unroll
    for (int j = 0; j < C_INST; ++j) myrow[j] = 0.f;   // own row: no sync

    const int4* __restrict__ tgt4 = (const int4*)(target + (size_t)b * HW_N);
    const float4* __restrict__ src4 =
        (const float4*)(input + ((size_t)b * E_DIM + eg) * HW_N);
    const int gbase = chunk * 256 * P1_ITER + tid;

    int scnt[C_INST];
    #pragma unroll
    for (int c = 0; c < C_INST; ++c) scnt[c] = 0;

    int4   lab = tgt4[gbase];
    float4 x   = src4[gbase];
    #pragma unroll
    for (int it = 0; it < P1_ITER; ++it) {
        const int4   lc = lab;
        const float4 xc = x;
        if (it + 1 < P1_ITER) {          // register prefetch
            lab = tgt4[gbase + (it + 1) * 256];
            x   = src4[gbase + (it + 1) * 256];
        }
        myrow[lc.x] += xc.x;
        myrow[lc.y] += xc.y;
        myrow[lc.z] += xc.z;
        myrow[lc.w] += xc.w;
        if (eg < 8 && it == eg) {        // uniform branch: count this slice
            #pragma unroll
            for (int c = 0; c < C_INST; ++c) {
                scnt[c] += (int)__popcll(__ballot(lc.x == c))
                         + (int)__popcll(__ballot(lc.y == c))
                         + (int)__popcll(__ballot(lc.z == c))
                         + (int)__popcll(__ballot(lc.w == c));
            }
        }
    }
    if (lane == 0) {
        #pragma unroll
        for (int c = 0; c < C_INST; ++c) crow[wv][c] = (float)scnt[c];
    }
    __syncthreads();

    // reduce 256 bucket rows -> 24 class sums; 8 threads per class
    if (tid < 8 * C_INST) {
        const int c  = tid >> 3;
        const int r0 = tid & 7;
        float s = 0.f;
        #pragma unroll
        for (int i = 0; i < 32; ++i) s += buk[8 * i + r0][c];
        s += __shfl_xor(s, 1, 64);
        s += __shfl_xor(s, 2, 64);
        s += __shfl_xor(s, 4, 64);
        if (r0 == 0)
            unsafeAtomicAdd(&sums[((size_t)b * E_DIM + eg) * C_INST + c], s);
    }
    if (eg < 8 && tid < C_INST) {
        const float s = crow[0][tid] + crow[1][tid] + crow[2][tid] + crow[3][tid];
        unsafeAtomicAdd(&counts[b * C_INST + tid], s);
    }
}

// ---------------------------------------------------------------------------
// Pass 2 (UNCHANGED from R9): variance term, per-block partial to a DISTINCT
// slot (no same-address atomic chain — R8 lesson). mu stride 17
// (conflict-free gathers).
// ---------------------------------------------------------------------------
__global__ __launch_bounds__(256) void pass2_kernel(
    const float* __restrict__ input, const int* __restrict__ target,
    const float* __restrict__ sums, const float* __restrict__ counts,
    float* __restrict__ partials)
{
    __shared__ float mu_l[C_INST][17];
    __shared__ float w_l[C_INST];
    __shared__ float redw[4];
    const int tid  = threadIdx.x;
    const int lane = tid & 63;
    const int wv   = tid >> 6;
    const int b    = blockIdx.y;

    if (tid < C_INST) {
        const float cv = counts[b * C_INST + tid];
        w_l[tid] = (cv > 0.f) ? 1.f / cv : 0.f;
    }
    __syncthreads();
    for (int i = tid; i < E_DIM * C_INST; i += 256) {
        const int e = i / C_INST, c = i % C_INST;
        mu_l[c][e] = sums[((size_t)b * E_DIM + e) * C_INST + c] * w_l[c];
    }
    __syncthreads();

    const int g = blockIdx.x * 256 + tid;    // 256 blocks/batch
    const int4 lab4 = ((const int4*)(target + (size_t)b * HW_N))[g];
    const float4* __restrict__ src4 =
        (const float4*)(input + (size_t)b * E_DIM * HW_N);

    float4 xv[E_DIM];
    #pragma unroll
    for (int e = 0; e < E_DIM; ++e)
        xv[e] = src4[(size_t)e * NG + g];

    float d2[4] = {0.f, 0.f, 0.f, 0.f};
    #pragma unroll
    for (int e = 0; e < E_DIM; ++e) {
        float df;
        df = xv[e].x - mu_l[lab4.x][e]; d2[0] = fmaf(df, df, d2[0]);
        df = xv[e].y - mu_l[lab4.y][e]; d2[1] = fmaf(df, df, d2[1]);
        df = xv[e].z - mu_l[lab4.z][e]; d2[2] = fmaf(df, df, d2[2]);
        df = xv[e].w - mu_l[lab4.w][e]; d2[3] = fmaf(df, df, d2[3]);
    }

    float vloc = 0.f;
    {
        const int lp[4] = {lab4.x, lab4.y, lab4.z, lab4.w};
        #pragma unroll
        for (int p = 0; p < 4; ++p) {
            const float h = fmaxf(sqrtf(d2[p]) - DELTA_VAR, 0.f);
            vloc = fmaf(h * h, w_l[lp[p]], vloc);
        }
    }
    #pragma unroll
    for (int m = 1; m < 64; m <<= 1) vloc += __shfl_xor(vloc, m, 64);
    if (lane == 0) redw[wv] = vloc;
    __syncthreads();
    if (tid == 0)
        partials[b * 256 + blockIdx.x] = redw[0] + redw[1] + redw[2] + redw[3];
}

// ---------------------------------------------------------------------------
// Final: sum 1024 partials + pairwise distance + regularizer -> loss.
// ---------------------------------------------------------------------------
__global__ __launch_bounds__(256) void final_kernel(
    const float* __restrict__ sums, const float* __restrict__ counts,
    const float* __restrict__ partials, float* __restrict__ out)
{
    __shared__ float mu[B_SZ][C_INST][E_DIM];
    __shared__ float red[256];
    const int tid = threadIdx.x;

    for (int i = tid; i < B_SZ * C_INST * E_DIM; i += 256) {
        const int b = i / (C_INST * E_DIM);
        const int r = i % (C_INST * E_DIM);
        const int e = r / C_INST, c = r % C_INST;
        const float cv = counts[b * C_INST + c];
        mu[b][c][e] = (cv > 0.f)
            ? sums[((size_t)b * E_DIM + e) * C_INST + c] / cv : 0.f;
    }
    __syncthreads();

    float acc = 0.f;
    // variance partials (1024 slots, 4 per thread)
    #pragma unroll
    for (int i = 0; i < P2_TOTAL_BLOCKS / 256; ++i)
        acc += partials[i * 256 + tid] * (ALPHA_W / (B_SZ * C_INST));
    // regularizer
    for (int i = tid; i < B_SZ * C_INST; i += 256) {
        const int b = i / C_INST, c = i % C_INST;
        float n2 = 0.f;
        #pragma unroll
        for (int e = 0; e < E_DIM; ++e) n2 += mu[b][c][e] * mu[b][c][e];
        acc += GAMMA_W * sqrtf(n2) * (1.0f / (B_SZ * C_INST));
    }
    // pairwise repulsion
    for (int i = tid; i < B_SZ * C_INST * C_INST; i += 256) {
        const int b  = i / (C_INST * C_INST);
        const int r  = i % (C_INST * C_INST);
        const int c1 = r / C_INST, c2 = r % C_INST;
        if (c1 != c2) {
            float d2 = 0.f;
            #pragma unroll
            for (int e = 0; e < E_DIM; ++e) {
                const float d = mu[b][c1][e] - mu[b][c2][e];
                d2 += d * d;
            }
            const float h = fmaxf(2.0f * DELTA_DIST - sqrtf(d2), 0.f);
            acc += BETA_W * h * h * (1.0f / (B_SZ * C_INST * (C_INST - 1)));
        }
    }

    red[tid] = acc;
    __syncthreads();
    for (int s = 128; s > 0; s >>= 1) {
        if (tid < s) red[tid] += red[tid + s];
        __syncthreads();
    }
    if (tid == 0) out[0] = red[0];
}

extern "C" void kernel_launch(void* const* d_in, const int* in_sizes, int n_in,
                              void* d_out, int out_size, void* d_ws, size_t ws_size,
                              hipStream_t stream)
{
    const float* input  = (const float*)d_in[0];
    const int*   target = (const int*)d_in[1];

    float* sums     = (float*)d_ws;                         // B*E*C ([b][e][c])
    float* counts   = sums + B_SZ * E_DIM * C_INST;         // B*C
    float* partials = counts + B_SZ * C_INST;               // 1024 (no zeroing needed)
    const size_t ws_zero_bytes =
        (size_t)(B_SZ * E_DIM * C_INST + B_SZ * C_INST) * sizeof(float);
    hipMemsetAsync(d_ws, 0, ws_zero_bytes, stream);

    pass1_kernel<<<dim3(P1_NB, E_DIM, B_SZ), 256, 0, stream>>>(input, target, sums, counts);
    pass2_kernel<<<dim3(256, B_SZ), 256, 0, stream>>>(input, target, sums, counts, partials);
    final_kernel<<<1, 256, 0, stream>>>(sums, counts, partials, (float*)d_out);
}